// Round 13
// baseline (1057.292 us; speedup 1.0000x reference)
//
#include <hip/hip_runtime.h>
#include <hip/hip_bf16.h>
#include <hip/hip_cooperative_groups.h>

namespace cg = cooperative_groups;

using f32x4  = __attribute__((ext_vector_type(4))) float;
using u32x4  = __attribute__((ext_vector_type(4))) unsigned int;
using bf16x8 = __attribute__((ext_vector_type(8))) short;

__device__ __forceinline__ ushort f2bf(float x) {
    union { __hip_bfloat16 h; ushort u; } cv;
    cv.h = __float2bfloat16(x);
    return cv.u;
}
__device__ __forceinline__ unsigned pk2(float lo, float hi) {
    return (unsigned)f2bf(lo) | ((unsigned)f2bf(hi) << 16);
}
__device__ __forceinline__ float sigmoidf_(float x) { return 1.f / (1.f + expf(-x)); }

// ---------------------------------------------------------------------------
// LDS GEMM body (verified since R2): C = A * B(bf16,[K,N]) variants.
// ---------------------------------------------------------------------------
template<int NSUM, bool A_BF16, bool ABR, bool SPLIT, bool RELU, bool BF16_OUT, bool HAS_BIAS>
__device__ __forceinline__ void gemm_body(
    ushort* As, ushort* Bs,
    const void* __restrict__ Avoid, const ushort* __restrict__ B,
    const float* __restrict__ abias, const float* __restrict__ bias,
    float* __restrict__ Cf, ushort* __restrict__ Cb,
    int M, int N, int K, int ldc, int kPerChunk, long pStride,
    int bx, int by, int bz)
{
    const int tid  = threadIdx.x;
    const int lane = tid & 63;
    const int wid  = tid >> 6;
    const int wr   = wid >> 1, wc = wid & 1;
    const int g    = lane >> 4, lr = lane & 15;
    const long m0  = (long)bx * 128;
    const int  n0  = by * 64;

    int kbeg = 0, kend = K;
    if (SPLIT) { kbeg = bz * kPerChunk; kend = kbeg + kPerChunk; if (kend > K) kend = K; }

    const int bkr = tid & 31;
    const int bcb = tid >> 5;

    const float*  Af = (const float*)Avoid;
    const ushort* Ab = (const ushort*)Avoid;

    f32x4 pa[4];
    u32x4 pab[2];
    u32x4 pb;

    auto loadT = [&](int k0) {
        if (A_BF16) {
#pragma unroll
            for (int i = 0; i < 2; i++) {
                int s = tid + 256 * i; int row = s >> 2, c8 = s & 3;
                pab[i] = *(const u32x4*)(Ab + (m0 + row) * (long)K + k0 + c8 * 8);
            }
        } else {
#pragma unroll
            for (int i = 0; i < 4; i++) {
                int s = tid + 256 * i; int row = s >> 3, c4 = s & 7;
                const float* base = Af + (m0 + row) * (long)K + k0 + c4 * 4;
                f32x4 v = *(const f32x4*)base;
                if (NSUM > 0) {
#pragma unroll
                    for (int z = 1; z < NSUM; z++) v += *(const f32x4*)(base + z * pStride);
                }
                if (ABR) {
                    f32x4 bq = *(const f32x4*)(abias + k0 + c4 * 4);
                    v.x = fmaxf(v.x + bq.x, 0.f);
                    v.y = fmaxf(v.y + bq.y, 0.f);
                    v.z = fmaxf(v.z + bq.z, 0.f);
                    v.w = fmaxf(v.w + bq.w, 0.f);
                }
                pa[i] = v;
            }
        }
        pb = *(const u32x4*)(B + (long)(k0 + bkr) * N + n0 + bcb * 8);
    };
    auto storeT = [&]() {
        if (A_BF16) {
#pragma unroll
            for (int i = 0; i < 2; i++) {
                int s = tid + 256 * i; int row = s >> 2, c8 = s & 3;
                *(u32x4*)(&As[row * 40 + c8 * 8]) = pab[i];
            }
        } else {
#pragma unroll
            for (int i = 0; i < 4; i++) {
                int s = tid + 256 * i; int row = s >> 3, c4 = s & 7;
                ushort4 w;
                w.x = f2bf(pa[i].x); w.y = f2bf(pa[i].y);
                w.z = f2bf(pa[i].z); w.w = f2bf(pa[i].w);
                *(ushort4*)(&As[row * 40 + c4 * 4]) = w;
            }
        }
        const ushort* p8 = (const ushort*)&pb;
#pragma unroll
        for (int j = 0; j < 8; j++) Bs[(bcb * 8 + j) * 40 + bkr] = p8[j];
    };

    f32x4 acc[4][2] = {};

    const int nk = (kend - kbeg) >> 5;
    loadT(kbeg);
    for (int t = 0; t < nk; ++t) {
        storeT();
        __syncthreads();
        if (t + 1 < nk) loadT(kbeg + ((t + 1) << 5));
        bf16x8 af[4], bfr[2];
#pragma unroll
        for (int fm = 0; fm < 4; fm++)
            af[fm] = *(const bf16x8*)(&As[(wr * 64 + fm * 16 + lr) * 40 + g * 8]);
#pragma unroll
        for (int fn = 0; fn < 2; fn++)
            bfr[fn] = *(const bf16x8*)(&Bs[(wc * 32 + fn * 16 + lr) * 40 + g * 8]);
#pragma unroll
        for (int fm = 0; fm < 4; fm++)
#pragma unroll
            for (int fn = 0; fn < 2; fn++)
                acc[fm][fn] = __builtin_amdgcn_mfma_f32_16x16x32_bf16(af[fm], bfr[fn], acc[fm][fn], 0, 0, 0);
        __syncthreads();
    }

    if (SPLIT) {
        float* P = Cf + (long)bz * M * N;
#pragma unroll
        for (int fm = 0; fm < 4; fm++)
#pragma unroll
            for (int fn = 0; fn < 2; fn++)
#pragma unroll
                for (int rr = 0; rr < 4; rr++) {
                    long row = m0 + wr * 64 + fm * 16 + g * 4 + rr;
                    int  col = n0 + wc * 32 + fn * 16 + lr;
                    P[row * N + col] = acc[fm][fn][rr];
                }
    } else {
#pragma unroll
        for (int fm = 0; fm < 4; fm++)
#pragma unroll
            for (int fn = 0; fn < 2; fn++)
#pragma unroll
                for (int rr = 0; rr < 4; rr++) {
                    long row = m0 + wr * 64 + fm * 16 + g * 4 + rr;
                    int  col = n0 + wc * 32 + fn * 16 + lr;
                    float v = acc[fm][fn][rr];
                    if (HAS_BIAS) v += bias[col];
                    if (RELU) v = fmaxf(v, 0.f);
                    if (BF16_OUT) Cb[row * ldc + col] = f2bf(v);
                    else          Cf[row * ldc + col] = v;
                }
    }
}

// ---------------------------------------------------------------------------
struct MegaArgs {
    const float *A, *Xn, *W1, *Xe, *Wh, *hb1, *W2;
    ushort *Abf, *T1, *Zt1, *W2t, *T2;
    const float *L1, *B1;
    float *stats;                 // gsum[64], gsq[64]
    float *Zc1, *Z1, *Z2, *sbuf, *rbuf, *Pa, *Pb;
    const float *gb1, *gb2, *bn1g, *bn1b, *hW2, *hb2, *bn2g, *bn2b;
    const float *nW, *nb, *eW, *eb, *yW, *yb;
    const void  *he;
    float *hcat, *out_node, *out_edge, *out_hyper;
};

// ---------------------------------------------------------------------------
__global__ __launch_bounds__(256, 4) void mega_k(MegaArgs a)
{
    cg::grid_group grid = cg::this_grid();
    __shared__ ushort As[128 * 40];   // 10240 B
    __shared__ ushort Bs[64 * 40];    //  5120 B
    const int G = gridDim.x;
    const int t = threadIdx.x;
    const int l = t & 63, w = t >> 6;

    // ---------------- P0: prep (11009 units) ----------------
    for (int u = blockIdx.x; u < 11009; u += G) {
        if (u < 8192) {                       // A convert, 8 elems/thread
            long j = (long)u * 256 + t;
            f32x4 v0 = ((const f32x4*)a.A)[2 * j];
            f32x4 v1 = ((const f32x4*)a.A)[2 * j + 1];
            u32x4 wv;
            wv.x = pk2(v0.x, v0.y); wv.y = pk2(v0.z, v0.w);
            wv.z = pk2(v1.x, v1.y); wv.w = pk2(v1.z, v1.w);
            ((u32x4*)a.Abf)[j] = wv;
        } else if (u < 8704) {                // T1: 8 rows/unit
            float* xs = (float*)As;
            int r0 = (u - 8192) * 8;
            __syncthreads();
            for (int idx = t; idx < 1024; idx += 256) xs[idx] = a.Xn[(long)r0 * 128 + idx];
            __syncthreads();
            float acc[8] = {};
            const float* wrow = a.W1 + (long)t * 128;
            for (int i = 0; i < 128; i++) {
                float wv = wrow[i];
#pragma unroll
                for (int r = 0; r < 8; r++) acc[r] += xs[r * 128 + i] * wv;
            }
#pragma unroll
            for (int r = 0; r < 8; r++) a.T1[(long)(r0 + r) * 256 + t] = f2bf(acc[r]);
        } else if (u < 10752) {               // Zt1: 4 rows/unit, wave/row
            int row = (u - 8704) * 4 + w;
            int o   = l;
            const float* xr = a.Xe + (long)row * 64;
            const float* wr = a.Wh + (long)o * 64;
            float acc = a.hb1[o];
#pragma unroll 8
            for (int i = 0; i < 64; i++) acc += xr[i] * wr[i];
            a.Zt1[(long)row * 64 + o] = f2bf(acc);
        } else if (u < 11008) {               // W2 transpose
            int j = (u - 10752) * 256 + t;
            int i = j >> 8, o = j & 255;
            a.W2t[j] = f2bf(a.W2[o * 256 + i]);
        } else {
            if (t < 128) a.stats[t] = 0.f;
        }
    }
    __threadfence();
    grid.sync();

    // ---------------- P1: K6 (512) + K1' (512) ----------------
    for (int u = blockIdx.x; u < 1024; u += G) {
        if (u < 512) {
            gemm_body<0, false, false, true, false, false, false>(
                As, Bs, a.L1, a.Zt1, nullptr, nullptr, a.Pa, nullptr,
                8192, 64, 8192, 64, 1024, 0, u & 63, 0, u >> 6);
        } else {
            int b = u - 512;
            gemm_body<0, true, false, true, false, false, false>(
                As, Bs, a.Abf, a.T1, nullptr, nullptr, a.Pb, nullptr,
                4096, 256, 4096, 256, 1024, 0, b & 31, (b >> 5) & 3, b >> 7);
        }
    }
    __threadfence();
    grid.sync();

    // ---------------- P2: T2 gemm (128) + bnred (256) ----------------
    for (int u = blockIdx.x; u < 384; u += G) {
        if (u < 128) {
            gemm_body<4, false, true, false, false, true, false>(
                As, Bs, a.Pb, a.W2t, a.gb1, nullptr, nullptr, a.T2,
                4096, 256, 256, 256, 0, (long)4096 * 256, u & 31, u >> 5, 0);
        } else {
            int b = u - 128;
            const long MN = 8192 * 64;
            int c = t & 63, rg = t >> 6;
            float sx = 0.f, sq = 0.f;
            int base = b * 32 + rg;
#pragma unroll 4
            for (int i = 0; i < 8; i++) {
                long idx = (long)(base + 4 * i) * 64 + c;
                float x = 0.f;
#pragma unroll
                for (int z = 0; z < 8; z++) x += a.Pa[idx + z * MN];
                a.Zc1[idx] = x;
                sx += x; sq += x * x;
            }
            float* ls = (float*)Bs;
            float* lq = ls + 256;
            __syncthreads();
            ls[t] = sx; lq[t] = sq;
            __syncthreads();
            if (t < 64) {
                float av = ls[t] + ls[t + 64] + ls[t + 128] + ls[t + 192];
                float qv = lq[t] + lq[t + 64] + lq[t + 128] + lq[t + 192];
                atomicAdd(&a.stats[t], av);
                atomicAdd(&a.stats[64 + t], qv);
            }
            __syncthreads();
        }
    }
    __threadfence();
    grid.sync();

    // ---------------- P3: K2' (512) + z1 (2048) ----------------
    for (int u = blockIdx.x; u < 2560; u += G) {
        if (u < 512) {
            gemm_body<0, true, false, true, false, false, false>(
                As, Bs, a.Abf, a.T2, nullptr, nullptr, a.Pa, nullptr,
                4096, 256, 4096, 256, 1024, 0, u & 31, (u >> 5) & 3, u >> 7);
        } else {
            int b = u - 512;
            int row = b * 4 + w;
            const float inv = 1.f / 8192.f;
            float m = a.stats[l] * inv;
            float v = a.stats[64 + l] * inv - m * m;
            float x = a.Zc1[row * 64 + l];
            float y = fmaxf(a.bn1g[l] * (x - m) * rsqrtf(v + 1e-5f) + a.bn1b[l], 0.f);
#pragma unroll
            for (int o = 32; o > 0; o >>= 1) y = fmaxf(y, __shfl_xor(y, o));
            if (l == 0) a.Z1[row] = y;
        }
    }
    __threadfence();
    grid.sync();

    // ---------------- P4: hcatred (1024) + pass2 (8192) ----------------
    for (int u = blockIdx.x; u < 9216; u += G) {
        if (u < 1024) {
            const long MNq = (long)4096 * 256 / 4;
            int j = u * 256 + t;
            int row = j >> 6, c4 = (j & 63) * 4;
            const f32x4* Q = (const f32x4*)a.Pa;
            f32x4 v = Q[j] + Q[j + MNq] + Q[j + 2 * MNq] + Q[j + 3 * MNq];
            f32x4 bq = *(const f32x4*)(a.gb2 + c4);
            float* dst = a.hcat + (long)row * 258 + c4;
            float2 lo = { fmaxf(v.x + bq.x, 0.f), fmaxf(v.y + bq.y, 0.f) };
            float2 hi = { fmaxf(v.z + bq.z, 0.f), fmaxf(v.w + bq.w, 0.f) };
            *(float2*)dst = lo;
            *(float2*)(dst + 2) = hi;
        } else {
            int row = u - 1024;
            const f32x4* rp = (const f32x4*)(a.L1 + (long)row * 8192);
            const f32x4* z4 = (const f32x4*)a.Z1;
            float as = 0.f, ar = 0.f;
#pragma unroll 4
            for (int k = 0; k < 8; k++) {
                f32x4 v = rp[t + 256 * k];
                f32x4 z = z4[t + 256 * k];
                as += v.x * z.x + v.y * z.y + v.z * z.z + v.w * z.w;
                ar += v.x + v.y + v.z + v.w;
            }
#pragma unroll
            for (int o = 32; o > 0; o >>= 1) { as += __shfl_xor(as, o); ar += __shfl_xor(ar, o); }
            float* sw = (float*)Bs;
            float* rw = sw + 4;
            __syncthreads();
            if (l == 0) { sw[w] = as; rw[w] = ar; }
            __syncthreads();
            if (t == 0) {
                a.sbuf[row] = sw[0] + sw[1] + sw[2] + sw[3];
                a.rbuf[row] = rw[0] + rw[1] + rw[2] + rw[3];
            }
            __syncthreads();
        }
    }
    __threadfence();
    grid.sync();

    // ---------------- P5: z2 + edge head (2048 units, inline stats) ------
    for (int u = blockIdx.x; u < 2048; u += G) {
        float Ss = 0, Sr = 0, Sss = 0, Srr = 0, Ssr = 0;
        for (int i = t; i < 8192; i += 256) {
            float sv = a.sbuf[i], rv = a.rbuf[i];
            Ss += sv; Sr += rv; Sss += sv * sv; Srr += rv * rv; Ssr += sv * rv;
        }
#pragma unroll
        for (int o = 32; o > 0; o >>= 1) {
            Ss += __shfl_xor(Ss, o); Sr += __shfl_xor(Sr, o);
            Sss += __shfl_xor(Sss, o); Srr += __shfl_xor(Srr, o); Ssr += __shfl_xor(Ssr, o);
        }
        float* buf = (float*)Bs;        // [4][5]
        __syncthreads();
        if (l == 0) { buf[w * 5 + 0] = Ss; buf[w * 5 + 1] = Sr; buf[w * 5 + 2] = Sss; buf[w * 5 + 3] = Srr; buf[w * 5 + 4] = Ssr; }
        __syncthreads();
        float S0 = buf[0] + buf[5] + buf[10] + buf[15];
        float S1 = buf[1] + buf[6] + buf[11] + buf[16];
        float S2 = buf[2] + buf[7] + buf[12] + buf[17];
        float S3 = buf[3] + buf[8] + buf[13] + buf[18];
        float S4 = buf[4] + buf[9] + buf[14] + buf[19];
        __syncthreads();

        int row = u * 4 + w;
        const float inv = 1.f / 8192.f;
        float ms = S0 * inv, mr = S1 * inv;
        float vs = S2 * inv - ms * ms;
        float vr = S3 * inv - mr * mr;
        float cv = S4 * inv - ms * mr;
        float w2 = a.hW2[l], bz = a.hb2[l];
        float mc = w2 * ms + bz * mr;
        float vc = w2 * w2 * vs + 2.f * w2 * bz * cv + bz * bz * vr;
        float x  = w2 * a.sbuf[row] + bz * a.rbuf[row];
        float y  = fmaxf(a.bn2g[l] * (x - mc) * rsqrtf(vc + 1e-5f) + a.bn2b[l], 0.f);
#pragma unroll
        for (int o = 32; o > 0; o >>= 1) y = fmaxf(y, __shfl_xor(y, o));
        if (l == 0) {
            a.Z2[row] = y;
            float e = a.Z1[row] * a.eW[0] + y * a.eW[1] + a.eb[0];
            a.out_edge[row] = sigmoidf_(e);
        }
    }
    __threadfence();
    grid.sync();

    // ---------------- P6: H_e + node head (4096 units) ----------------
    for (int u = blockIdx.x; u < 4096; u += G) {
        int n = u;
        const f32x4* rp  = (const f32x4*)(a.B1 + (long)n * 8192);
        const f32x4* z1v = (const f32x4*)a.Z1;
        const f32x4* z2v = (const f32x4*)a.Z2;
        float a1 = 0.f, a2 = 0.f;
#pragma unroll 4
        for (int k = 0; k < 8; k++) {
            f32x4 v = rp[t + 256 * k];
            f32x4 p = z1v[t + 256 * k];
            f32x4 q = z2v[t + 256 * k];
            a1 += v.x * p.x + v.y * p.y + v.z * p.z + v.w * p.w;
            a2 += v.x * q.x + v.y * q.y + v.z * q.z + v.w * q.w;
        }
        float d = a.hcat[(long)n * 258 + t] * a.nW[t];
#pragma unroll
        for (int o = 32; o > 0; o >>= 1) {
            a1 += __shfl_xor(a1, o); a2 += __shfl_xor(a2, o); d += __shfl_xor(d, o);
        }
        float* s1 = (float*)Bs;
        float* s2 = s1 + 4;
        float* s3 = s2 + 4;
        __syncthreads();
        if (l == 0) { s1[w] = a1; s2[w] = a2; s3[w] = d; }
        __syncthreads();
        if (t == 0) {
            float A1 = s1[0] + s1[1] + s1[2] + s1[3];
            float A2 = s2[0] + s2[1] + s2[2] + s2[3];
            float D  = s3[0] + s3[1] + s3[2] + s3[3];
            a.hcat[(long)n * 258 + 256] = A1;
            a.hcat[(long)n * 258 + 257] = A2;
            a.out_node[n] = sigmoidf_(D + A1 * a.nW[256] + A2 * a.nW[257] + a.nb[0]);
        }
        __syncthreads();
    }
    __threadfence();
    grid.sync();

    // ---------------- P7: hyper head (256 units) ----------------
    for (int u = blockIdx.x; u < 256; u += G) {
        int h = u * 4 + w;
        const unsigned int* uu = (const unsigned int*)a.he;
        unsigned int odd = uu[2 * l + 1];
        bool is64 = __all(odd == 0u);
        float acc = 0.f;
        for (int k = 0; k < 8; k++) {
            int idx;
            if (is64) idx = (int)((const long long*)a.he)[h * 8 + k];
            else      idx = ((const int*)a.he)[h * 8 + k];
            const float* hr = a.hcat + (long)idx * 258;
            for (int d = l; d < 258; d += 64) acc += hr[d] * a.yW[d];
        }
        acc *= 0.125f;
#pragma unroll
        for (int o = 32; o > 0; o >>= 1) acc += __shfl_xor(acc, o);
        if (l == 0) a.out_hyper[h] = sigmoidf_(acc + a.yb[0]);
    }
}

// ---------------------------------------------------------------------------
extern "C" void kernel_launch(void* const* d_in, const int* in_sizes, int n_in,
                              void* d_out, int out_size, void* d_ws, size_t ws_size,
                              hipStream_t stream)
{
    const float* X_n  = (const float*)d_in[0];
    const float* X_e  = (const float*)d_in[1];
    const float* A_t  = (const float*)d_in[2];
    const float* L1   = (const float*)d_in[3];
    const float* B1   = (const float*)d_in[4];
    const float* gW1  = (const float*)d_in[5];
    const float* gb1  = (const float*)d_in[6];
    const float* gW2  = (const float*)d_in[7];
    const float* gb2  = (const float*)d_in[8];
    const float* hW1  = (const float*)d_in[9];
    const float* hb1  = (const float*)d_in[10];
    const float* bn1g = (const float*)d_in[11];
    const float* bn1b = (const float*)d_in[12];
    const float* hW2  = (const float*)d_in[13];
    const float* hb2  = (const float*)d_in[14];
    const float* bn2g = (const float*)d_in[15];
    const float* bn2b = (const float*)d_in[16];
    const float* nW   = (const float*)d_in[17];
    const float* nb   = (const float*)d_in[18];
    const float* eW   = (const float*)d_in[19];
    const float* ebb  = (const float*)d_in[20];
    const float* yW   = (const float*)d_in[21];
    const float* yb   = (const float*)d_in[22];
    const void*  he   = d_in[23];

    float* out       = (float*)d_out;
    float* out_node  = out;              // 4096
    float* out_edge  = out + 4096;       // 8192
    float* out_hyper = out + 12288;      // 1024
    float* hcat      = out + 13312;      // 4096 x 258

    size_t off = 0;
    auto alloc = [&](size_t bytes) {
        void* p = (char*)d_ws + off;
        off = (off + bytes + 255) & ~(size_t)255;
        return p;
    };
    ushort* Abf    = (ushort*)alloc((size_t)4096 * 4096 * 2);
    ushort* T1     = (ushort*)alloc(4096 * 256 * 2);
    ushort* T2     = (ushort*)alloc(4096 * 256 * 2);
    ushort* Zt1    = (ushort*)alloc(8192 * 64 * 2);
    ushort* W2t    = (ushort*)alloc(256 * 256 * 2);
    float*  Zc1    = (float*)alloc(8192 * 64 * 4);
    float*  stats  = (float*)alloc(256 * 4);
    float*  Z1     = (float*)alloc(8192 * 4);
    float*  Z2     = (float*)alloc(8192 * 4);
    float*  sbuf   = (float*)alloc(8192 * 4);
    float*  rbuf   = (float*)alloc(8192 * 4);
    float*  Pa     = (float*)alloc((size_t)8192 * 64 * 8 * 4);
    float*  Pb     = (float*)alloc((size_t)4096 * 256 * 4 * 4);

    MegaArgs a;
    a.A = A_t; a.Xn = X_n; a.W1 = gW1; a.Xe = X_e; a.Wh = hW1; a.hb1 = hb1; a.W2 = gW2;
    a.Abf = Abf; a.T1 = T1; a.Zt1 = Zt1; a.W2t = W2t; a.T2 = T2;
    a.L1 = L1; a.B1 = B1;
    a.stats = stats;
    a.Zc1 = Zc1; a.Z1 = Z1; a.Z2 = Z2; a.sbuf = sbuf; a.rbuf = rbuf; a.Pa = Pa; a.Pb = Pb;
    a.gb1 = gb1; a.gb2 = gb2; a.bn1g = bn1g; a.bn1b = bn1b;
    a.hW2 = hW2; a.hb2 = hb2; a.bn2g = bn2g; a.bn2b = bn2b;
    a.nW = nW; a.nb = nb; a.eW = eW; a.eb = ebb; a.yW = yW; a.yb = yb;
    a.he = he;
    a.hcat = hcat; a.out_node = out_node; a.out_edge = out_edge; a.out_hyper = out_hyper;

    int maxB = 0;
    hipOccupancyMaxActiveBlocksPerMultiprocessor(&maxB, (const void*)mega_k, 256, 0);
    if (maxB < 1) maxB = 1;
    long grid = (long)maxB * 256;        // 256 CUs on MI355X
    if (grid > 2048) grid = 2048;

    void* params[] = { &a };
    hipLaunchCooperativeKernel((const void*)mega_k, dim3((unsigned)grid), dim3(256),
                               params, 0, stream);
}

// Round 14
// 295.968 us; speedup vs baseline: 3.5723x; 3.5723x over previous
//
#include <hip/hip_runtime.h>
#include <hip/hip_bf16.h>

using f32x4  = __attribute__((ext_vector_type(4))) float;
using u32x4  = __attribute__((ext_vector_type(4))) unsigned int;
using bf16x8 = __attribute__((ext_vector_type(8))) short;

__device__ __forceinline__ ushort f2bf(float x) {
    union { __hip_bfloat16 h; ushort u; } cv;
    cv.h = __float2bfloat16(x);
    return cv.u;
}
__device__ __forceinline__ unsigned pk2(float lo, float hi) {
    return (unsigned)f2bf(lo) | ((unsigned)f2bf(hi) << 16);
}
__device__ __forceinline__ float sigmoidf_(float x) { return 1.f / (1.f + expf(-x)); }

// ---------------------------------------------------------------------------
// LDS GEMM body: C[M,N] = A * B where B is PRE-TRANSPOSED BT[N][K] bf16.
// A: bf16 | f32 | sum of NSUM f32 partial chunks (pStride apart), opt
// +abias[k]+relu (ABR). BM=128, BN=64, BK=32; 4 waves (2x2), wave tile 64x32.
// B staging: thread (tid) loads BT[n0 + tid>>2][k0 + (tid&3)*8 .. +8] (16B)
// and stores one ds_write_b128 into Bs[n][k] (pitch 40) — no scalar transpose.
// CT_OUT: bf16 output written TRANSPOSED: Cb[col*M + row] (for T2T).
// ---------------------------------------------------------------------------
template<int NSUM, bool A_BF16, bool ABR, bool SPLIT, bool RELU, bool BF16_OUT, bool CT_OUT, bool HAS_BIAS>
__device__ __forceinline__ void gemm_body(
    ushort* As, ushort* Bs,
    const void* __restrict__ Avoid, const ushort* __restrict__ BT,
    const float* __restrict__ abias, const float* __restrict__ bias,
    float* __restrict__ Cf, ushort* __restrict__ Cb,
    int M, int N, int K, int ldc, int kPerChunk, long pStride,
    int bx, int by, int bz)
{
    const int tid  = threadIdx.x;
    const int lane = tid & 63;
    const int wid  = tid >> 6;
    const int wr   = wid >> 1, wc = wid & 1;
    const int g    = lane >> 4, lr = lane & 15;
    const long m0  = (long)bx * 128;
    const int  n0  = by * 64;

    int kbeg = 0, kend = K;
    if (SPLIT) { kbeg = bz * kPerChunk; kend = kbeg + kPerChunk; if (kend > K) kend = K; }

    const int bn = tid >> 2;        // B row (n) within tile: 0..63
    const int bk = (tid & 3) * 8;   // B k-offset within tile: 0,8,16,24

    const float*  Af = (const float*)Avoid;
    const ushort* Ab = (const ushort*)Avoid;

    f32x4 pa[4];
    u32x4 pab[2];
    u32x4 pb;

    auto loadT = [&](int k0) {
        if (A_BF16) {
#pragma unroll
            for (int i = 0; i < 2; i++) {
                int s = tid + 256 * i; int row = s >> 2, c8 = s & 3;
                pab[i] = *(const u32x4*)(Ab + (m0 + row) * (long)K + k0 + c8 * 8);
            }
        } else {
#pragma unroll
            for (int i = 0; i < 4; i++) {
                int s = tid + 256 * i; int row = s >> 3, c4 = s & 7;
                const float* base = Af + (m0 + row) * (long)K + k0 + c4 * 4;
                f32x4 v = *(const f32x4*)base;
                if (NSUM > 0) {
#pragma unroll
                    for (int z = 1; z < NSUM; z++) v += *(const f32x4*)(base + z * pStride);
                }
                if (ABR) {
                    f32x4 bq = *(const f32x4*)(abias + k0 + c4 * 4);
                    v.x = fmaxf(v.x + bq.x, 0.f);
                    v.y = fmaxf(v.y + bq.y, 0.f);
                    v.z = fmaxf(v.z + bq.z, 0.f);
                    v.w = fmaxf(v.w + bq.w, 0.f);
                }
                pa[i] = v;
            }
        }
        pb = *(const u32x4*)(BT + (long)(n0 + bn) * K + k0 + bk);
    };
    auto storeT = [&]() {
        if (A_BF16) {
#pragma unroll
            for (int i = 0; i < 2; i++) {
                int s = tid + 256 * i; int row = s >> 2, c8 = s & 3;
                *(u32x4*)(&As[row * 40 + c8 * 8]) = pab[i];
            }
        } else {
#pragma unroll
            for (int i = 0; i < 4; i++) {
                int s = tid + 256 * i; int row = s >> 3, c4 = s & 7;
                ushort4 w;
                w.x = f2bf(pa[i].x); w.y = f2bf(pa[i].y);
                w.z = f2bf(pa[i].z); w.w = f2bf(pa[i].w);
                *(ushort4*)(&As[row * 40 + c4 * 4]) = w;
            }
        }
        *(u32x4*)(&Bs[bn * 40 + bk]) = pb;   // single vector LDS store
    };

    f32x4 acc[4][2] = {};

    const int nk = (kend - kbeg) >> 5;
    loadT(kbeg);
    for (int t = 0; t < nk; ++t) {
        storeT();
        __syncthreads();
        if (t + 1 < nk) loadT(kbeg + ((t + 1) << 5));
        bf16x8 af[4], bfr[2];
#pragma unroll
        for (int fm = 0; fm < 4; fm++)
            af[fm] = *(const bf16x8*)(&As[(wr * 64 + fm * 16 + lr) * 40 + g * 8]);
#pragma unroll
        for (int fn = 0; fn < 2; fn++)
            bfr[fn] = *(const bf16x8*)(&Bs[(wc * 32 + fn * 16 + lr) * 40 + g * 8]);
#pragma unroll
        for (int fm = 0; fm < 4; fm++)
#pragma unroll
            for (int fn = 0; fn < 2; fn++)
                acc[fm][fn] = __builtin_amdgcn_mfma_f32_16x16x32_bf16(af[fm], bfr[fn], acc[fm][fn], 0, 0, 0);
        __syncthreads();
    }

    if (SPLIT) {
        float* P = Cf + (long)bz * M * N;
#pragma unroll
        for (int fm = 0; fm < 4; fm++)
#pragma unroll
            for (int fn = 0; fn < 2; fn++)
#pragma unroll
                for (int rr = 0; rr < 4; rr++) {
                    long row = m0 + wr * 64 + fm * 16 + g * 4 + rr;
                    int  col = n0 + wc * 32 + fn * 16 + lr;
                    P[row * N + col] = acc[fm][fn][rr];
                }
    } else if (CT_OUT) {
#pragma unroll
        for (int fm = 0; fm < 4; fm++)
#pragma unroll
            for (int fn = 0; fn < 2; fn++) {
                long row0 = m0 + wr * 64 + fm * 16 + g * 4;
                int  col  = n0 + wc * 32 + fn * 16 + lr;
                ushort4 w;
                w.x = f2bf(fmaxf(acc[fm][fn][0], RELU ? 0.f : acc[fm][fn][0]));
                // (RELU not used on CT_OUT path; keep simple)
                w.x = f2bf(acc[fm][fn][0]);
                w.y = f2bf(acc[fm][fn][1]);
                w.z = f2bf(acc[fm][fn][2]);
                w.w = f2bf(acc[fm][fn][3]);
                *(ushort4*)(Cb + (long)col * M + row0) = w;
            }
    } else {
#pragma unroll
        for (int fm = 0; fm < 4; fm++)
#pragma unroll
            for (int fn = 0; fn < 2; fn++)
#pragma unroll
                for (int rr = 0; rr < 4; rr++) {
                    long row = m0 + wr * 64 + fm * 16 + g * 4 + rr;
                    int  col = n0 + wc * 32 + fn * 16 + lr;
                    float v = acc[fm][fn][rr];
                    if (HAS_BIAS) v += bias[col];
                    if (RELU) v = fmaxf(v, 0.f);
                    if (BF16_OUT) Cb[row * ldc + col] = f2bf(v);
                    else          Cf[row * ldc + col] = v;
                }
    }
}

// ---------------------------------------------------------------------------
// 1. prep: A->bf16 | T1T[o][row] = Xn@W1^T | Zt1T[o][row] = Xe@Wh^T + hb |
//    W2 -> bf16 (NO transpose: W2 row-major IS BT for the T2 gemm) | zero stats.
//    11009 blocks.
// ---------------------------------------------------------------------------
__global__ __launch_bounds__(256)
void prep_k(const float* __restrict__ A, ushort* __restrict__ Abf,
            const float* __restrict__ Xn, const float* __restrict__ W1, ushort* __restrict__ T1T,
            const float* __restrict__ Xe, const float* __restrict__ Wh,
            const float* __restrict__ hb, ushort* __restrict__ Zt1T,
            const float* __restrict__ W2, ushort* __restrict__ W2b,
            float* __restrict__ stats)
{
    __shared__ float xs[1024];
    int b = blockIdx.x, t = threadIdx.x;
    if (b < 8192) {                       // A convert, 8 elems/thread
        long j = (long)b * 256 + t;
        f32x4 v0 = ((const f32x4*)A)[2 * j];
        f32x4 v1 = ((const f32x4*)A)[2 * j + 1];
        u32x4 w;
        w.x = pk2(v0.x, v0.y); w.y = pk2(v0.z, v0.w);
        w.z = pk2(v1.x, v1.y); w.w = pk2(v1.z, v1.w);
        ((u32x4*)Abf)[j] = w;
    } else if (b < 8704) {                // T1T: 8 rows per block, thread = out col
        int r0 = (b - 8192) * 8;
        for (int idx = t; idx < 1024; idx += 256) xs[idx] = Xn[(long)r0 * 128 + idx];
        __syncthreads();
        float acc[8] = {};
        const float* wrow = W1 + (long)t * 128;
        for (int i = 0; i < 128; i++) {
            float w = wrow[i];
#pragma unroll
            for (int r = 0; r < 8; r++) acc[r] += xs[r * 128 + i] * w;
        }
        ushort w8[8];
#pragma unroll
        for (int r = 0; r < 8; r++) w8[r] = f2bf(acc[r]);
        *(u32x4*)(T1T + (long)t * 4096 + r0) = *(u32x4*)w8;   // transposed, 16B
    } else if (b < 10752) {               // Zt1T: 4 rows/block, wave per row
        int row = (b - 8704) * 4 + (t >> 6);
        int o   = t & 63;
        const float* xr = Xe + (long)row * 64;
        const float* wr = Wh + (long)o * 64;
        float acc = hb[o];
#pragma unroll 8
        for (int i = 0; i < 64; i++) acc += xr[i] * wr[i];
        Zt1T[(long)o * 8192 + row] = f2bf(acc);   // transposed store
    } else if (b < 11008) {               // W2 -> bf16 straight copy
        int j = (b - 10752) * 256 + t;
        W2b[j] = f2bf(W2[j]);
    } else {
        if (t < 256) stats[t] = 0.f;      // gsum[64], gsq[64], S5@128
    }
}

// ---------------------------------------------------------------------------
// bnred: Zc1 = sum of 8 partial chunks; col stats via per-address atomics
// (256 adds/address — cheap).  256 blocks.
// ---------------------------------------------------------------------------
__device__ __forceinline__ void bnred_body(int b, const float* __restrict__ P,
                                           float* __restrict__ Zc,
                                           float* __restrict__ gsum, float* __restrict__ gsq)
{
    const long MN = 8192 * 64;
    int t = threadIdx.x;
    int c = t & 63, rg = t >> 6;
    float sx = 0.f, sq = 0.f;
    int base = b * 32 + rg;
#pragma unroll 4
    for (int i = 0; i < 8; i++) {
        long idx = (long)(base + 4 * i) * 64 + c;
        float x = 0.f;
#pragma unroll
        for (int z = 0; z < 8; z++) x += P[idx + z * MN];
        Zc[idx] = x;
        sx += x; sq += x * x;
    }
    __shared__ float ls[256], lq[256];
    ls[t] = sx; lq[t] = sq;
    __syncthreads();
    if (t < 64) {
        float a = ls[t] + ls[t + 64] + ls[t + 128] + ls[t + 192];
        float q = lq[t] + lq[t + 64] + lq[t + 128] + lq[t + 192];
        atomicAdd(&gsum[t], a);
        atomicAdd(&gsq[t], q);
    }
}

__device__ __forceinline__ void z1_body(int b, const float* __restrict__ Zc,
                                        const float* __restrict__ gsum, const float* __restrict__ gsq,
                                        const float* __restrict__ g, const float* __restrict__ bb,
                                        float* __restrict__ Z1)
{
    int w = threadIdx.x >> 6, lane = threadIdx.x & 63;
    int row = b * 4 + w;
    const float inv = 1.f / 8192.f;
    float m = gsum[lane] * inv;
    float v = gsq[lane] * inv - m * m;
    float x = Zc[row * 64 + lane];
    float y = fmaxf(g[lane] * (x - m) * rsqrtf(v + 1e-5f) + bb[lane], 0.f);
#pragma unroll
    for (int o = 32; o > 0; o >>= 1) y = fmaxf(y, __shfl_xor(y, o));
    if (lane == 0) Z1[row] = y;
}

__device__ __forceinline__ void pass2_body(int row, const float* __restrict__ L1,
                                           const float* __restrict__ Z1,
                                           float* __restrict__ s, float* __restrict__ r)
{
    int t = threadIdx.x;
    int l = t & 63, w = t >> 6;
    const f32x4* rp = (const f32x4*)(L1 + (long)row * 8192);
    const f32x4* z4 = (const f32x4*)Z1;
    float as = 0.f, ar = 0.f;
#pragma unroll 4
    for (int k = 0; k < 8; k++) {
        f32x4 v = rp[t + 256 * k];
        f32x4 z = z4[t + 256 * k];
        as += v.x * z.x + v.y * z.y + v.z * z.z + v.w * z.w;
        ar += v.x + v.y + v.z + v.w;
    }
#pragma unroll
    for (int o = 32; o > 0; o >>= 1) { as += __shfl_xor(as, o); ar += __shfl_xor(ar, o); }
    __shared__ float sw[4], rw[4];
    if (l == 0) { sw[w] = as; rw[w] = ar; }
    __syncthreads();
    if (t == 0) {
        s[row] = sw[0] + sw[1] + sw[2] + sw[3];
        r[row] = rw[0] + rw[1] + rw[2] + rw[3];
    }
}

// hcat reduce: hcat[:, 0:256] = relu(sum of 4 chunks of P + b2); 1024 blocks
__device__ __forceinline__ void hcatred_body(int b, const float* __restrict__ P,
                                             const float* __restrict__ b2, float* __restrict__ hcat)
{
    const long MNq = (long)4096 * 256 / 4;
    int j = b * 256 + threadIdx.x;
    int row = j >> 6, c4 = (j & 63) * 4;
    const f32x4* Q = (const f32x4*)P;
    f32x4 v = Q[j] + Q[j + MNq] + Q[j + 2 * MNq] + Q[j + 3 * MNq];
    f32x4 bq = *(const f32x4*)(b2 + c4);
    float* dst = hcat + (long)row * 258 + c4;
    float2 lo = { fmaxf(v.x + bq.x, 0.f), fmaxf(v.y + bq.y, 0.f) };
    float2 hi = { fmaxf(v.z + bq.z, 0.f), fmaxf(v.w + bq.w, 0.f) };
    *(float2*)dst = lo;
    *(float2*)(dst + 2) = hi;
}

// ---------------------------------------------------------------------------
// merged launches
// ---------------------------------------------------------------------------
// dual_a: [0,512) K6: L1@Zt1T^T split8 -> Pa ; [512,1024) K1': Abf@T1T^T split4 -> Pb
__global__ __launch_bounds__(256)
void dual_a_k(const float* __restrict__ L1, const ushort* __restrict__ Zt1T, float* __restrict__ Pa,
              const ushort* __restrict__ Abf, const ushort* __restrict__ T1T, float* __restrict__ Pb)
{
    __shared__ ushort As[128 * 40];
    __shared__ ushort Bs[64 * 40];
    int bid = blockIdx.x;
    if (bid < 512) {
        gemm_body<0, false, false, true, false, false, false, false>(
            As, Bs, L1, Zt1T, nullptr, nullptr, Pa, nullptr,
            8192, 64, 8192, 64, 1024, 0, bid & 63, 0, bid >> 6);
    } else {
        int b = bid - 512;
        gemm_body<0, true, false, true, false, false, false, false>(
            As, Bs, Abf, T1T, nullptr, nullptr, Pb, nullptr,
            4096, 256, 4096, 256, 1024, 0, b & 31, (b >> 5) & 3, b >> 7);
    }
}

// dual_b: [0,128) T2T = [(sum4 Pb + b1).relu] @ W2b^T, output TRANSPOSED ;
//         [128,384) bnred (8 chunks)
__global__ __launch_bounds__(256)
void dual_b_k(const float* __restrict__ Pb, const float* __restrict__ gb1,
              const ushort* __restrict__ W2b, ushort* __restrict__ T2T,
              const float* __restrict__ Pa, float* __restrict__ Zc1,
              float* __restrict__ gsum, float* __restrict__ gsq)
{
    __shared__ ushort As[128 * 40];
    __shared__ ushort Bs[64 * 40];
    int bid = blockIdx.x;
    if (bid < 128) {
        gemm_body<4, false, true, false, false, true, true, false>(
            As, Bs, Pb, W2b, gb1, nullptr, nullptr, T2T,
            4096, 256, 256, 256, 0, (long)4096 * 256, bid & 31, bid >> 5, 0);
    } else {
        bnred_body(bid - 128, Pa, Zc1, gsum, gsq);
    }
}

// dual_c: [0,512) K2': Abf@T2T^T split4 -> Pa ; [512,2560) z1
__global__ __launch_bounds__(256)
void dual_c_k(const ushort* __restrict__ Abf, const ushort* __restrict__ T2T, float* __restrict__ Pa,
              const float* __restrict__ Zc1, const float* __restrict__ gsum,
              const float* __restrict__ gsq, const float* __restrict__ bn1g,
              const float* __restrict__ bn1b, float* __restrict__ Z1)
{
    __shared__ ushort As[128 * 40];
    __shared__ ushort Bs[64 * 40];
    int bid = blockIdx.x;
    if (bid < 512) {
        gemm_body<0, true, false, true, false, false, false, false>(
            As, Bs, Abf, T2T, nullptr, nullptr, Pa, nullptr,
            4096, 256, 4096, 256, 1024, 0, bid & 31, (bid >> 5) & 3, bid >> 7);
    } else {
        z1_body(bid - 512, Zc1, gsum, gsq, bn1g, bn1b, Z1);
    }
}

// dual_d: [0,1024) hcat reduce ; [1024,9216) pass2
__global__ __launch_bounds__(256)
void dual_d_k(const float* __restrict__ Pa, const float* __restrict__ gb2, float* __restrict__ hcat,
              const float* __restrict__ L1, const float* __restrict__ Z1,
              float* __restrict__ s, float* __restrict__ r)
{
    int bid = blockIdx.x;
    if (bid < 1024) hcatred_body(bid, Pa, gb2, hcat);
    else            pass2_body(bid - 1024, L1, Z1, s, r);
}

// single block (1024 thr): 5 moments of (s, r) over 8192 rows
__global__ __launch_bounds__(1024) void stats2_k(const float* __restrict__ s, const float* __restrict__ r,
                                                 float* __restrict__ S5)
{
    int t = threadIdx.x, l = t & 63, w = t >> 6;
    float Ss = 0, Sr = 0, Sss = 0, Srr = 0, Ssr = 0;
    for (int i = t; i < 8192; i += 1024) {
        float sv = s[i], rv = r[i];
        Ss += sv; Sr += rv; Sss += sv * sv; Srr += rv * rv; Ssr += sv * rv;
    }
#pragma unroll
    for (int o = 32; o > 0; o >>= 1) {
        Ss += __shfl_xor(Ss, o); Sr += __shfl_xor(Sr, o);
        Sss += __shfl_xor(Sss, o); Srr += __shfl_xor(Srr, o); Ssr += __shfl_xor(Ssr, o);
    }
    __shared__ float buf[16][5];
    if (l == 0) { buf[w][0] = Ss; buf[w][1] = Sr; buf[w][2] = Sss; buf[w][3] = Srr; buf[w][4] = Ssr; }
    __syncthreads();
    if (t < 5) {
        float a = 0.f;
#pragma unroll
        for (int i = 0; i < 16; i++) a += buf[i][t];
        S5[t] = a;
    }
}

// Z2 + edge_prob; wave per row; grid 2048 x 256
__global__ __launch_bounds__(256) void z2_edge_k(const float* __restrict__ s, const float* __restrict__ r,
                                                 const float* __restrict__ S,
                                                 const float* __restrict__ W2, const float* __restrict__ b2,
                                                 const float* __restrict__ g2, const float* __restrict__ bb2,
                                                 const float* __restrict__ eW, const float* __restrict__ eb,
                                                 const float* __restrict__ Z1,
                                                 float* __restrict__ Z2, float* __restrict__ edge_out)
{
    int w = threadIdx.x >> 6, lane = threadIdx.x & 63;
    int row = blockIdx.x * 4 + w;
    const float inv = 1.f / 8192.f;
    float ms = S[0] * inv, mr = S[1] * inv;
    float vs = S[2] * inv - ms * ms;
    float vr = S[3] * inv - mr * mr;
    float cv = S[4] * inv - ms * mr;
    float w2 = W2[lane], bz = b2[lane];
    float mc = w2 * ms + bz * mr;
    float vc = w2 * w2 * vs + 2.f * w2 * bz * cv + bz * bz * vr;
    float x  = w2 * s[row] + bz * r[row];
    float y  = fmaxf(g2[lane] * (x - mc) * rsqrtf(vc + 1e-5f) + bb2[lane], 0.f);
#pragma unroll
    for (int o = 32; o > 0; o >>= 1) y = fmaxf(y, __shfl_xor(y, o));
    if (lane == 0) {
        Z2[row] = y;
        float e = Z1[row] * eW[0] + y * eW[1] + eb[0];
        edge_out[row] = sigmoidf_(e);
    }
}

// H_e (B1@[Z1 Z2]) into hcat cols 256/257 + node head; block per row, grid 4096
__global__ __launch_bounds__(256) void he_node_k(const float* __restrict__ B1, const float* __restrict__ Z1,
                                                 const float* __restrict__ Z2, float* __restrict__ hcat,
                                                 const float* __restrict__ nW, const float* __restrict__ nb,
                                                 float* __restrict__ node_out)
{
    int n = blockIdx.x, t = threadIdx.x;
    int l = t & 63, w = t >> 6;
    const f32x4* rp  = (const f32x4*)(B1 + (long)n * 8192);
    const f32x4* z1v = (const f32x4*)Z1;
    const f32x4* z2v = (const f32x4*)Z2;
    float a1 = 0.f, a2 = 0.f;
#pragma unroll 4
    for (int k = 0; k < 8; k++) {
        f32x4 v = rp[t + 256 * k];
        f32x4 p = z1v[t + 256 * k];
        f32x4 q = z2v[t + 256 * k];
        a1 += v.x * p.x + v.y * p.y + v.z * p.z + v.w * p.w;
        a2 += v.x * q.x + v.y * q.y + v.z * q.z + v.w * q.w;
    }
    float d = hcat[(long)n * 258 + t] * nW[t];
#pragma unroll
    for (int o = 32; o > 0; o >>= 1) {
        a1 += __shfl_xor(a1, o); a2 += __shfl_xor(a2, o); d += __shfl_xor(d, o);
    }
    __shared__ float s1[4], s2[4], s3[4];
    if (l == 0) { s1[w] = a1; s2[w] = a2; s3[w] = d; }
    __syncthreads();
    if (t == 0) {
        float A1 = s1[0] + s1[1] + s1[2] + s1[3];
        float A2 = s2[0] + s2[1] + s2[2] + s2[3];
        float D  = s3[0] + s3[1] + s3[2] + s3[3];
        hcat[(long)n * 258 + 256] = A1;
        hcat[(long)n * 258 + 257] = A2;
        node_out[n] = sigmoidf_(D + A1 * nW[256] + A2 * nW[257] + nb[0]);
    }
}

// hyperedge gather-mean-dot-sigmoid; wave per hyperedge; grid 256 x 256
__global__ __launch_bounds__(256) void hyper_k(const void* __restrict__ he_idx,
                                               const float* __restrict__ hcat,
                                               const float* __restrict__ hW, const float* __restrict__ hb,
                                               float* __restrict__ out)
{
    int w = threadIdx.x >> 6, lane = threadIdx.x & 63;
    int h = blockIdx.x * 4 + w;
    const unsigned int* u = (const unsigned int*)he_idx;
    unsigned int odd = u[2 * lane + 1];
    bool is64 = __all(odd == 0u);
    float acc = 0.f;
    for (int k = 0; k < 8; k++) {
        int idx;
        if (is64) idx = (int)((const long long*)he_idx)[h * 8 + k];
        else      idx = ((const int*)he_idx)[h * 8 + k];
        const float* hr = hcat + (long)idx * 258;
        for (int d = lane; d < 258; d += 64) acc += hr[d] * hW[d];
    }
    acc *= 0.125f;
#pragma unroll
    for (int o = 32; o > 0; o >>= 1) acc += __shfl_xor(acc, o);
    if (lane == 0) out[h] = sigmoidf_(acc + hb[0]);
}

// ---------------------------------------------------------------------------
extern "C" void kernel_launch(void* const* d_in, const int* in_sizes, int n_in,
                              void* d_out, int out_size, void* d_ws, size_t ws_size,
                              hipStream_t stream)
{
    const float* X_n  = (const float*)d_in[0];
    const float* X_e  = (const float*)d_in[1];
    const float* A_t  = (const float*)d_in[2];
    const float* L1   = (const float*)d_in[3];
    const float* B1   = (const float*)d_in[4];
    const float* gW1  = (const float*)d_in[5];
    const float* gb1  = (const float*)d_in[6];
    const float* gW2  = (const float*)d_in[7];
    const float* gb2  = (const float*)d_in[8];
    const float* hW1  = (const float*)d_in[9];
    const float* hb1  = (const float*)d_in[10];
    const float* bn1g = (const float*)d_in[11];
    const float* bn1b = (const float*)d_in[12];
    const float* hW2  = (const float*)d_in[13];
    const float* hb2  = (const float*)d_in[14];
    const float* bn2g = (const float*)d_in[15];
    const float* bn2b = (const float*)d_in[16];
    const float* nW   = (const float*)d_in[17];
    const float* nb   = (const float*)d_in[18];
    const float* eW   = (const float*)d_in[19];
    const float* ebb  = (const float*)d_in[20];
    const float* yW   = (const float*)d_in[21];
    const float* yb   = (const float*)d_in[22];
    const void*  he   = d_in[23];

    float* out       = (float*)d_out;
    float* out_node  = out;              // 4096
    float* out_edge  = out + 4096;       // 8192
    float* out_hyper = out + 12288;      // 1024
    float* hcat      = out + 13312;      // 4096 x 258

    size_t off = 0;
    auto alloc = [&](size_t bytes) {
        void* p = (char*)d_ws + off;
        off = (off + bytes + 255) & ~(size_t)255;
        return p;
    };
    ushort* Abf    = (ushort*)alloc((size_t)4096 * 4096 * 2);  // 33.5 MB
    ushort* T1T    = (ushort*)alloc(4096 * 256 * 2);           // [256][4096]
    ushort* T2T    = (ushort*)alloc(4096 * 256 * 2);           // [256][4096]
    ushort* Zt1T   = (ushort*)alloc(8192 * 64 * 2);            // [64][8192]
    ushort* W2b    = (ushort*)alloc(256 * 256 * 2);            // [256][256] row-major
    float*  Zc1    = (float*)alloc(8192 * 64 * 4);
    float*  stats  = (float*)alloc(256 * 4);   // gsum[64], gsq[64], S5@128
    float*  gsum   = stats;
    float*  gsq    = stats + 64;
    float*  S5     = stats + 128;
    float*  Z1     = (float*)alloc(8192 * 4);
    float*  Z2     = (float*)alloc(8192 * 4);
    float*  sbuf   = (float*)alloc(8192 * 4);
    float*  rbuf   = (float*)alloc(8192 * 4);
    float*  Pa     = (float*)alloc((size_t)8192 * 64 * 8 * 4); // 16.8 MB
    float*  Pb     = (float*)alloc((size_t)4096 * 256 * 4 * 4); // 16.8 MB

    // 1. prep
    prep_k<<<11009, 256, 0, stream>>>(A_t, Abf, X_n, gW1, T1T, X_e, hW1, hb1, Zt1T,
                                      gW2, W2b, stats);

    // 2. dual_a: {L1@Zt1 split8 -> Pa} || {Abf@T1 split4 -> Pb}
    dual_a_k<<<1024, 256, 0, stream>>>(L1, Zt1T, Pa, Abf, T1T, Pb);

    // 3. dual_b: {T2T = relu(sum4 Pb + b1)@W2^T (transposed out)} || {bnred}
    dual_b_k<<<384, 256, 0, stream>>>(Pb, gb1, W2b, T2T, Pa, Zc1, gsum, gsq);

    // 4. dual_c: {Abf@T2 split4 -> Pa} || {z1}
    dual_c_k<<<2560, 256, 0, stream>>>(Abf, T2T, Pa, Zc1, gsum, gsq, bn1g, bn1b, Z1);

    // 5. dual_d: {hcat = relu(sum4 Pa + b2)} || {pass2: s, r}
    dual_d_k<<<9216, 256, 0, stream>>>(Pa, gb2, hcat, L1, Z1, sbuf, rbuf);

    // 6. stats2 (single block)
    stats2_k<<<1, 1024, 0, stream>>>(sbuf, rbuf, S5);

    // 7. z2 + edge head
    z2_edge_k<<<2048, 256, 0, stream>>>(sbuf, rbuf, S5, hW2, hb2, bn2g, bn2b,
                                        eW, ebb, Z1, Z2, out_edge);

    // 8. H_e + node head
    he_node_k<<<4096, 256, 0, stream>>>(B1, Z1, Z2, hcat, nW, nb, out_node);

    // 9. hyper head
    hyper_k<<<256, 256, 0, stream>>>(he, hcat, yW, yb, out_hyper);
}